// Round 4
// baseline (974.264 us; speedup 1.0000x reference)
//
#include <hip/hip_runtime.h>

#define NN 1000
#define HEADS_ 4
#define DM 128
#define EE 64000
#define NTOT 4000
#define ETOT 68000
#define CAP 48     // bucket holds ALL edges per dst: deg ~ Poisson(16)+1, P(>=48) ~ 1e-11
#define EB 34      // edge-builder blocks appended to the h-GEMM dispatch

// -------- K1: blocks 0..499 = h-GEMM (250 m-tiles of 64 rows x 2 n-tiles) + score
//              blocks 500..499+EB = bucket build
// 64x64 tile, K=64, frag 4x4, 32 KB LDS -> 2+ blocks/CU.
__global__ __launch_bounds__(256) void k1_kernel(const float* __restrict__ x,
                                                 const float* __restrict__ W,
                                                 const float* __restrict__ att,
                                                 float* __restrict__ hbuf,
                                                 float* __restrict__ ssrc,
                                                 float* __restrict__ sdst,
                                                 const int* __restrict__ ei,
                                                 int* __restrict__ cnt,
                                                 int* __restrict__ elist) {
  int bid = blockIdx.x;
  if (bid < 500) {
    __shared__ float As[64 * 64];
    __shared__ float Bs[64 * 64];
    int tid = threadIdx.x;
    int mi = bid >> 1, ni = bid & 1;
    int m0 = mi * 64, n0 = ni * 64;
    int tx = tid & 15, ty = tid >> 4;
    const float4* A4 = (const float4*)x;   // [16000][16]
    const float4* W4 = (const float4*)W;   // [128][16]
    float acc[4][4] = {};

    {
      int q = tid & 15, r0 = tid >> 4;
#pragma unroll
      for (int p = 0; p < 4; ++p) {  // A: 64 rows
        int r = r0 + p * 16;
        float4 v = A4[(size_t)(m0 + r) * 16 + q];
        *(float4*)&As[r * 64 + ((q ^ ((r >> 2) & 15)) << 2)] = v;
      }
#pragma unroll
      for (int p = 0; p < 4; ++p) {  // B: 64 rows
        int r = r0 + p * 16;
        float4 v = W4[(size_t)(n0 + r) * 16 + q];
        *(float4*)&Bs[r * 64 + ((q ^ ((r >> 2) & 15)) << 2)] = v;
      }
    }
    __syncthreads();
#pragma unroll 4
    for (int q = 0; q < 16; ++q) {
      float4 a[4], b[4];
      int sa = (q ^ ty) << 2;          // (r>>2)&15 == ty for r=ty*4+i
      int sb = (q ^ tx) << 2;
#pragma unroll
      for (int i = 0; i < 4; ++i)
        a[i] = *(const float4*)&As[(ty * 4 + i) * 64 + sa];
#pragma unroll
      for (int j = 0; j < 4; ++j)
        b[j] = *(const float4*)&Bs[(tx * 4 + j) * 64 + sb];
#pragma unroll
      for (int i = 0; i < 4; ++i)
#pragma unroll
        for (int j = 0; j < 4; ++j)
          acc[i][j] += a[i].x * b[j].x + a[i].y * b[j].y
                     + a[i].z * b[j].z + a[i].w * b[j].w;
    }

    int nc = n0 + tx * 4;
#pragma unroll
    for (int i = 0; i < 4; ++i) {
      int m = m0 + ty * 4 + i;
      *(float4*)&hbuf[(size_t)m * DM + nc] =
          make_float4(acc[i][0], acc[i][1], acc[i][2], acc[i][3]);
    }

    if (m0 < NN) {  // fused GAT score epilogue (rows < 1000 only)
      int hsel = tx >> 3;
      int h = ni * 2 + hsel;
      int kb = (tx & 7) * 4;
      float a0[4], a1[4];
#pragma unroll
      for (int j = 0; j < 4; ++j) {
        a0[j] = att[h * 64 + kb + j];
        a1[j] = att[h * 64 + 32 + kb + j];
      }
#pragma unroll
      for (int i = 0; i < 4; ++i) {
        int m = m0 + ty * 4 + i;
        float p0 = 0.f, p1 = 0.f;
#pragma unroll
        for (int j = 0; j < 4; ++j) {
          float g = acc[i][j];
          float lr = g > 0.f ? g : 0.2f * g;
          p0 += a0[j] * lr;
          p1 += a1[j] * lr;
        }
        p0 += __shfl_xor(p0, 1, 16); p1 += __shfl_xor(p1, 1, 16);
        p0 += __shfl_xor(p0, 2, 16); p1 += __shfl_xor(p1, 2, 16);
        p0 += __shfl_xor(p0, 4, 16); p1 += __shfl_xor(p1, 4, 16);
        if ((tx & 7) == 0 && m < NN) {
          ssrc[m * HEADS_ + h] = p0;
          sdst[m * HEADS_ + h] = p1;
        }
      }
    }
  } else {
    for (int e = (bid - 500) * 256 + threadIdx.x; e < ETOT; e += EB * 256) {
      int s, d;
      if (e < EE) { s = ei[e]; d = ei[EE + e]; }
      else { s = d = e - EE; }  // self loops
      int pos = atomicAdd(&cnt[d], 1);
      if (pos < CAP) elist[d * CAP + pos] = s;
    }
  }
}

// -------- K2: gather with in-block softmax (local denom), 2 dst/block.
// Inner loop 4x-unrolled with clamped unconditional loads -> 4x MLP.
__global__ __launch_bounds__(256) void gather_kernel(const int* __restrict__ cnt,
                                                     const int* __restrict__ elist,
                                                     const float* __restrict__ ssrc,
                                                     const float* __restrict__ sdst,
                                                     const float* __restrict__ hbuf,
                                                     float* __restrict__ hgat) {
  __shared__ int   srcs[2][CAP];
  __shared__ float exs[2][CAP][HEADS_];
  int li = threadIdx.x >> 7;
  int t = threadIdx.x & 127;
  int d = blockIdx.x * 2 + li;  // global dst node id
  int b = d / NN;
  int v = t >> 5, q = t & 31, h = q >> 3;
  int m = cnt[d]; if (m > CAP) m = CAP;
  for (int base = 0; base < m; base += 32) {
    int i = base + (t >> 2);
    if (i < m) {
      int s = elist[d * CAP + i];
      if ((t & 3) == 0) srcs[li][i] = s;
      float sc = ssrc[s * HEADS_ + (t & 3)] + sdst[d * HEADS_ + (t & 3)];
      exs[li][i][t & 3] = __expf(sc);  // shift-invariant, scores O(1)
    }
  }
  __syncthreads();
  // denom over ALL edges; numerator only same-block srcs (h_full block-diag)
  float den = 1e-16f;
  float4 acc = make_float4(0.f, 0.f, 0.f, 0.f);
  const float* hbase = hbuf + ((size_t)(b * 4 + v) * NN) * DM + q * 4;
  int i = 0;
  for (; i + 4 <= m; i += 4) {
    float ex[4]; unsigned sl[4]; float4 hv[4];
#pragma unroll
    for (int u = 0; u < 4; ++u) {
      ex[u] = exs[li][i + u][h];
      sl[u] = (unsigned)(srcs[li][i + u] - b * NN);
      unsigned sls = sl[u] < NN ? sl[u] : 0u;       // clamped, always-valid addr
      hv[u] = *(const float4*)(hbase + (size_t)sls * DM);
    }
#pragma unroll
    for (int u = 0; u < 4; ++u) {
      den += ex[u];
      float w = sl[u] < NN ? ex[u] : 0.f;
      acc.x += w * hv[u].x; acc.y += w * hv[u].y;
      acc.z += w * hv[u].z; acc.w += w * hv[u].w;
    }
  }
  for (; i < m; ++i) {
    float ex = exs[li][i][h];
    den += ex;
    unsigned sl = (unsigned)(srcs[li][i] - b * NN);
    if (sl < NN) {
      float4 hv = *(const float4*)(hbase + (size_t)sl * DM);
      acc.x += ex * hv.x; acc.y += ex * hv.y;
      acc.z += ex * hv.z; acc.w += ex * hv.w;
    }
  }
  float r = 1.f / den;
  acc.x *= r; acc.y *= r; acc.z *= r; acc.w *= r;
  *(float4*)&hgat[((size_t)(d * 4 + v)) * DM + q * 4] = acc;  // node-major
}

// ---------------------------------------------------------------------------
// fused3 v4: v3's register-attention structure + register discipline.
//  - #pragma unroll 1 on both K-chunk loops: staging loads cannot be hoisted
//    across chunks (R3's 256-VGPR / 540 MB scratch-spill catastrophe).
//  - inner q-iter: a[4] once, then per p in {q,k,v} load bq[4] and accumulate
//    -> peak fragment 8 float4 (32 VGPR) instead of 16 (64).
//  - __launch_bounds__(256,3): cap VGPR ~168, matching 3 blk/CU (52 KB LDS).
// Thread = (rg = tid&7 : node, cg = tid>>3 : d-group). Wave w holds head w's
// full 32 d-cols -> score reduce = 3 shfl_xor rounds; softmax + aw@v in regs.
// ---------------------------------------------------------------------------
__global__ __launch_bounds__(256, 3) void fused3_kernel(const float* __restrict__ hgat,
                                                        const float* __restrict__ inw,
                                                        const float* __restrict__ inb,
                                                        const float* __restrict__ outw,
                                                        const float* __restrict__ outb,
                                                        const float* __restrict__ bias,
                                                        float* __restrict__ out) {
  __shared__ float smem[13312];   // 53248 B
  float* Bs  = smem;              // [384 cols][32 k] swizzled (qkv weights)
  float* As  = smem + 12288;      // [32 rows][32 k] swizzled (hgat chunk)
  float* aoS = smem + 4096;       // [4 kc][32 rows][32] (post-qkv overlay)
  float* Ws2 = smem;              // [128 ocols][32 k] out_proj chunk overlay

  int tid = threadIdx.x;
  int rg = tid & 7;       // node within tile
  int cg = tid >> 3;      // d-group: d = 4cg..4cg+3
  int blk = blockIdx.x;
  int r0 = blk * 32;      // first hgat row (node blk*8, view 0)

  const float4* H4 = (const float4*)hgat;  // [16000][32]
  const float4* W4 = (const float4*)inw;   // [384][32]

  float acc[3][4][4] = {};  // [p: q/k/v][vq: view][j: d-sub]

#pragma unroll 1
  for (int c = 0; c < 4; ++c) {   // K chunks of 32 — NOT unrolled (reg bound)
    __syncthreads();
    {  // stage As: 256 float4, 1/thread, coalesced (kg fast)
      int r = tid >> 3, kg = tid & 7;
      float4 vv = H4[(size_t)(r0 + r) * 32 + c * 8 + kg];
      *(float4*)&As[r * 32 + ((kg ^ ((r >> 2) & 7)) << 2)] = vv;
    }
#pragma unroll
    for (int tt = 0; tt < 12; ++tt) {  // stage Bs: 3072 float4, coalesced
      int idx = tt * 256 + tid;
      int col = idx >> 3, kg = idx & 7;
      float4 vv = W4[(size_t)col * 32 + c * 8 + kg];
      *(float4*)&Bs[col * 32 + ((kg ^ ((col >> 2) & 7)) << 2)] = vv;
    }
    __syncthreads();
#pragma unroll
    for (int q = 0; q < 8; ++q) {
      float4 a[4];
      int ga = (q ^ rg) << 2;             // (r>>2)&7 == rg for r=rg*4+i
      int gb = (q ^ (cg & 7)) << 2;       // (col>>2)&7 == cg&7
#pragma unroll
      for (int i = 0; i < 4; ++i)
        a[i] = *(const float4*)&As[(rg * 4 + i) * 32 + ga];
#pragma unroll
      for (int p = 0; p < 3; ++p) {       // q/k/v serially: 8-float4 peak frag
        float4 bq[4];
#pragma unroll
        for (int j = 0; j < 4; ++j)
          bq[j] = *(const float4*)&Bs[(p * 128 + cg * 4 + j) * 32 + gb];
#pragma unroll
        for (int i = 0; i < 4; ++i)
#pragma unroll
          for (int j = 0; j < 4; ++j)
            acc[p][i][j] += a[i].x * bq[j].x + a[i].y * bq[j].y
                          + a[i].z * bq[j].z + a[i].w * bq[j].w;
      }
    }
  }

  // ---- + in_proj bias ----
  {
    float4 ib0 = *(const float4*)&inb[cg * 4];
    float4 ib1 = *(const float4*)&inb[128 + cg * 4];
    float4 ib2 = *(const float4*)&inb[256 + cg * 4];
#pragma unroll
    for (int i = 0; i < 4; ++i) {
      acc[0][i][0] += ib0.x; acc[0][i][1] += ib0.y; acc[0][i][2] += ib0.z; acc[0][i][3] += ib0.w;
      acc[1][i][0] += ib1.x; acc[1][i][1] += ib1.y; acc[1][i][2] += ib1.z; acc[1][i][3] += ib1.w;
      acc[2][i][0] += ib2.x; acc[2][i][1] += ib2.y; acc[2][i][2] += ib2.z; acc[2][i][3] += ib2.w;
    }
  }

  // ---- attention, all-register: S[vq][vk] partial over this thread's 4 d ----
  float S[4][4];
#pragma unroll
  for (int vq = 0; vq < 4; ++vq)
#pragma unroll
    for (int vk = 0; vk < 4; ++vk)
      S[vq][vk] = acc[0][vq][0] * acc[1][vk][0] + acc[0][vq][1] * acc[1][vk][1]
                + acc[0][vq][2] * acc[1][vk][2] + acc[0][vq][3] * acc[1][vk][3];
  // reduce over the head's 8 cg-lanes (lane = (cg&7)*8 + rg)
#pragma unroll
  for (int vq = 0; vq < 4; ++vq)
#pragma unroll
    for (int vk = 0; vk < 4; ++vk) {
      float s = S[vq][vk];
      s += __shfl_xor(s, 8);
      s += __shfl_xor(s, 16);
      s += __shfl_xor(s, 32);
      S[vq][vk] = s * 0.17677669529663687f;  // 1/sqrt(32)
    }
  // softmax over vk, per vq (redundant across 8 lanes, consistent)
#pragma unroll
  for (int vq = 0; vq < 4; ++vq) {
    float mx = fmaxf(fmaxf(S[vq][0], S[vq][1]), fmaxf(S[vq][2], S[vq][3]));
    float e0 = __expf(S[vq][0] - mx), e1 = __expf(S[vq][1] - mx);
    float e2 = __expf(S[vq][2] - mx), e3 = __expf(S[vq][3] - mx);
    float inv = 1.f / (e0 + e1 + e2 + e3);
    S[vq][0] = e0 * inv; S[vq][1] = e1 * inv; S[vq][2] = e2 * inv; S[vq][3] = e3 * inv;
  }
  // ao[vq][j] = sum_vk aw * v  (v frag is lane-local!)
  float ao_r[4][4];
#pragma unroll
  for (int vq = 0; vq < 4; ++vq)
#pragma unroll
    for (int j = 0; j < 4; ++j)
      ao_r[vq][j] = S[vq][0] * acc[2][0][j] + S[vq][1] * acc[2][1][j]
                  + S[vq][2] * acc[2][2][j] + S[vq][3] * acc[2][3][j];

  __syncthreads();  // qkv reads of Bs done before ao/Ws2 overlay
  {
    int kc = cg >> 3, d4 = cg & 7;
#pragma unroll
    for (int vq = 0; vq < 4; ++vq) {
      int r = rg * 4 + vq;
      *(float4*)&aoS[kc * 1024 + r * 32 + ((d4 ^ rg) << 2)] =
          make_float4(ao_r[vq][0], ao_r[vq][1], ao_r[vq][2], ao_r[vq][3]);
    }
  }

  // ---- out_proj: 32x128, K=128 in 4 chunks; frag 4x4 ----
  int rg2 = tid & 7, og = tid >> 3;   // rows rg2*4+i, cols og*4+j
  float oc[4][4] = {};
  const float4* O4 = (const float4*)outw;  // [128][32]
#pragma unroll 1
  for (int kc = 0; kc < 4; ++kc) {   // NOT unrolled (reg bound)
    __syncthreads();   // (first one also publishes aoS)
    {  // stage outw chunk: 1024 float4, 4/thread, coalesced
#pragma unroll
      for (int tt = 0; tt < 4; ++tt) {
        int idx = tt * 256 + tid;
        int col = idx >> 3, kg = idx & 7;
        float4 vv = O4[(size_t)col * 32 + kc * 8 + kg];
        *(float4*)&Ws2[col * 32 + ((kg ^ ((col >> 2) & 7)) << 2)] = vv;
      }
    }
    __syncthreads();
#pragma unroll
    for (int q = 0; q < 8; ++q) {
      float4 a[4], bq[4];
      int ga = (q ^ rg2) << 2;
      int gb = (q ^ (og & 7)) << 2;
#pragma unroll
      for (int i = 0; i < 4; ++i)
        a[i] = *(const float4*)&aoS[kc * 1024 + (rg2 * 4 + i) * 32 + ga];
#pragma unroll
      for (int j = 0; j < 4; ++j)
        bq[j] = *(const float4*)&Ws2[(og * 4 + j) * 32 + gb];
#pragma unroll
      for (int i = 0; i < 4; ++i)
#pragma unroll
        for (int j = 0; j < 4; ++j)
          oc[i][j] += a[i].x * bq[j].x + a[i].y * bq[j].y
                    + a[i].z * bq[j].z + a[i].w * bq[j].w;
    }
  }

  {  // epilogue: +outb +bias, remap row (node,v) -> (b*4+v)*NN + n
    int nc = og * 4;
    float4 ob = make_float4(outb[nc] + bias[nc], outb[nc + 1] + bias[nc + 1],
                            outb[nc + 2] + bias[nc + 2], outb[nc + 3] + bias[nc + 3]);
#pragma unroll
    for (int i = 0; i < 4; ++i) {
      int node = blk * 8 + rg2, vv = i;
      int bg = node / NN, n = node - bg * NN;
      int om = (bg * 4 + vv) * NN + n;
      *(float4*)&out[(size_t)om * DM + nc] =
          make_float4(oc[i][0] + ob.x, oc[i][1] + ob.y,
                      oc[i][2] + ob.z, oc[i][3] + ob.w);
    }
  }
}

extern "C" void kernel_launch(void* const* d_in, const int* in_sizes, int n_in,
                              void* d_out, int out_size, void* d_ws, size_t ws_size,
                              hipStream_t stream) {
  const float* x    = (const float*)d_in[0];
  const float* W    = (const float*)d_in[1];
  const float* att  = (const float*)d_in[2];
  const float* inw  = (const float*)d_in[3];
  const float* inb  = (const float*)d_in[4];
  const float* outw = (const float*)d_in[5];
  const float* outb = (const float*)d_in[6];
  const float* bias = (const float*)d_in[7];
  const int*   ei   = (const int*)d_in[8];
  float* out = (float*)d_out;

  float* ws = (float*)d_ws;
  float* hbuf  = ws;                       // 2,048,000  (b,v,n)-major h
  float* hgat  = ws + 2100000;             // 2,048,000  node-major
  float* ssrc  = ws + 12500000;            // 16,000 } contiguous:
  float* sdst  = ssrc + 16000;             // 16,000 } one 144 KB memset
  int*   cnt   = (int*)(sdst + 16000);     //  4,000 }
  int*   elist = cnt + 4000;               // 192,000 (4000 x CAP)

  // zero ssrc/sdst (rows >=1000 must stay zero) + cnt
  hipMemsetAsync(ssrc, 0, 36000 * sizeof(float), stream);

  k1_kernel<<<500 + EB, 256, 0, stream>>>(x, W, att, hbuf, ssrc, sdst, ei, cnt, elist);
  gather_kernel<<<NTOT / 2, 256, 0, stream>>>(cnt, elist, ssrc, sdst, hbuf, hgat);
  fused3_kernel<<<500, 256, 0, stream>>>(hgat, inw, inb, outw, outb, bias, out);
}

// Round 5
// 148.532 us; speedup vs baseline: 6.5593x; 6.5593x over previous
//
#include <hip/hip_runtime.h>

#define NN 1000
#define HEADS_ 4
#define DM 128
#define EE 64000
#define NTOT 4000
#define ETOT 68000
#define CAP 48     // bucket holds ALL edges per dst: deg ~ Poisson(16)+1, P(>=48) ~ 1e-11
#define EB 34      // edge-builder blocks appended to the h-GEMM dispatch

// ---------------------------------------------------------------------------
// 64x64 GEMM tile, K = KK (64 or 128): C[m0..+64][n0..+64] = A @ Wt^T (+b1).
// k-group swizzle g = q ^ ((r>>2)&15) (R2-proven: staging free, a-reads free,
// b-reads 2-way = free per m136). acc[4][4] only across the staged c-loop --
// the liveness pattern proven spill-free at 60 VGPR in R2.
// SCORE: fused GAT score epilogue (rows < 1000 only).
// ---------------------------------------------------------------------------
template <int KK, int SCORE>
__device__ void gemm64(int mi, int ni,
                       const float* __restrict__ A, const float* __restrict__ Wt,
                       const float* __restrict__ b1,
                       float* __restrict__ C, int N,
                       const float* __restrict__ att,
                       float* __restrict__ ssrc, float* __restrict__ sdst) {
  __shared__ float As[64 * 64];
  __shared__ float Bs[64 * 64];
  int tid = threadIdx.x;
  int m0 = mi * 64, n0 = ni * 64;
  int tx = tid & 15, ty = tid >> 4;
  const float4* A4 = (const float4*)A;
  const float4* W4 = (const float4*)Wt;
  float acc[4][4] = {};

  for (int c = 0; c < KK / 64; ++c) {
    __syncthreads();
    {
      int q = tid & 15, r0 = tid >> 4;
#pragma unroll
      for (int p = 0; p < 4; ++p) {  // A: 64 rows
        int r = r0 + p * 16;
        float4 v = A4[(size_t)(m0 + r) * (KK / 4) + c * 16 + q];
        *(float4*)&As[r * 64 + ((q ^ ((r >> 2) & 15)) << 2)] = v;
      }
#pragma unroll
      for (int p = 0; p < 4; ++p) {  // B: 64 rows
        int r = r0 + p * 16;
        float4 v = W4[(size_t)(n0 + r) * (KK / 4) + c * 16 + q];
        *(float4*)&Bs[r * 64 + ((q ^ ((r >> 2) & 15)) << 2)] = v;
      }
    }
    __syncthreads();
#pragma unroll 4
    for (int q = 0; q < 16; ++q) {
      float4 a[4], b[4];
      int sa = (q ^ ty) << 2;          // (r>>2)&15 == ty for r=ty*4+i
      int sb = (q ^ tx) << 2;
#pragma unroll
      for (int i = 0; i < 4; ++i)
        a[i] = *(const float4*)&As[(ty * 4 + i) * 64 + sa];
#pragma unroll
      for (int j = 0; j < 4; ++j)
        b[j] = *(const float4*)&Bs[(tx * 4 + j) * 64 + sb];
#pragma unroll
      for (int i = 0; i < 4; ++i)
#pragma unroll
        for (int j = 0; j < 4; ++j)
          acc[i][j] += a[i].x * b[j].x + a[i].y * b[j].y
                     + a[i].z * b[j].z + a[i].w * b[j].w;
    }
  }

  int nc = n0 + tx * 4;
  float4 bd = make_float4(0.f, 0.f, 0.f, 0.f);
  if (b1) bd = *(const float4*)&b1[nc];
#pragma unroll
  for (int i = 0; i < 4; ++i) {
    int m = m0 + ty * 4 + i;
    *(float4*)&C[(size_t)m * N + nc] =
        make_float4(acc[i][0] + bd.x, acc[i][1] + bd.y,
                    acc[i][2] + bd.z, acc[i][3] + bd.w);
  }

  if (SCORE && m0 < NN) {  // uniform per block
    int hsel = tx >> 3;
    int h = ni * 2 + hsel;
    int kb = (tx & 7) * 4;
    float a0[4], a1[4];
#pragma unroll
    for (int j = 0; j < 4; ++j) {
      a0[j] = att[h * 64 + kb + j];
      a1[j] = att[h * 64 + 32 + kb + j];
    }
#pragma unroll
    for (int i = 0; i < 4; ++i) {
      int m = m0 + ty * 4 + i;
      float p0 = 0.f, p1 = 0.f;
#pragma unroll
      for (int j = 0; j < 4; ++j) {
        float g = acc[i][j];
        float lr = g > 0.f ? g : 0.2f * g;
        p0 += a0[j] * lr;
        p1 += a1[j] * lr;
      }
      p0 += __shfl_xor(p0, 1, 16); p1 += __shfl_xor(p1, 1, 16);
      p0 += __shfl_xor(p0, 2, 16); p1 += __shfl_xor(p1, 2, 16);
      p0 += __shfl_xor(p0, 4, 16); p1 += __shfl_xor(p1, 4, 16);
      if ((tx & 7) == 0 && m < NN) {
        ssrc[m * HEADS_ + h] = p0;
        sdst[m * HEADS_ + h] = p1;
      }
    }
  }
}

// -------- K1: blocks 0..499 = h-GEMM (250 m-tiles x 2 n-tiles) + score
//              blocks 500..499+EB = bucket build
__global__ __launch_bounds__(256) void k1_kernel(const float* __restrict__ x,
                                                 const float* __restrict__ W,
                                                 const float* __restrict__ att,
                                                 float* __restrict__ hbuf,
                                                 float* __restrict__ ssrc,
                                                 float* __restrict__ sdst,
                                                 const int* __restrict__ ei,
                                                 int* __restrict__ cnt,
                                                 int* __restrict__ elist) {
  int bid = blockIdx.x;
  if (bid < 500) {
    gemm64<64, 1>(bid >> 1, bid & 1, x, W, nullptr, hbuf, 128, att, ssrc, sdst);
  } else {
    for (int e = (bid - 500) * 256 + threadIdx.x; e < ETOT; e += EB * 256) {
      int s, d;
      if (e < EE) { s = ei[e]; d = ei[EE + e]; }
      else { s = d = e - EE; }  // self loops
      int pos = atomicAdd(&cnt[d], 1);
      if (pos < CAP) elist[d * CAP + pos] = s;
    }
  }
}

// -------- K2: gather with in-block softmax (local denom), 2 dst/block.
// Inner loop 4x-unrolled with clamped unconditional loads -> 4x MLP.
__global__ __launch_bounds__(256) void gather_kernel(const int* __restrict__ cnt,
                                                     const int* __restrict__ elist,
                                                     const float* __restrict__ ssrc,
                                                     const float* __restrict__ sdst,
                                                     const float* __restrict__ hbuf,
                                                     float* __restrict__ hgat) {
  __shared__ int   srcs[2][CAP];
  __shared__ float exs[2][CAP][HEADS_];
  int li = threadIdx.x >> 7;
  int t = threadIdx.x & 127;
  int d = blockIdx.x * 2 + li;  // global dst node id
  int b = d / NN;
  int v = t >> 5, q = t & 31, h = q >> 3;
  int m = cnt[d]; if (m > CAP) m = CAP;
  for (int base = 0; base < m; base += 32) {
    int i = base + (t >> 2);
    if (i < m) {
      int s = elist[d * CAP + i];
      if ((t & 3) == 0) srcs[li][i] = s;
      float sc = ssrc[s * HEADS_ + (t & 3)] + sdst[d * HEADS_ + (t & 3)];
      exs[li][i][t & 3] = __expf(sc);  // shift-invariant, scores O(1)
    }
  }
  __syncthreads();
  // denom over ALL edges; numerator only same-block srcs (h_full block-diag)
  float den = 1e-16f;
  float4 acc = make_float4(0.f, 0.f, 0.f, 0.f);
  const float* hbase = hbuf + ((size_t)(b * 4 + v) * NN) * DM + q * 4;
  int i = 0;
  for (; i + 4 <= m; i += 4) {
    float ex[4]; unsigned sl[4]; float4 hv[4];
#pragma unroll
    for (int u = 0; u < 4; ++u) {
      ex[u] = exs[li][i + u][h];
      sl[u] = (unsigned)(srcs[li][i + u] - b * NN);
      unsigned sls = sl[u] < NN ? sl[u] : 0u;       // clamped, always-valid addr
      hv[u] = *(const float4*)(hbase + (size_t)sls * DM);
    }
#pragma unroll
    for (int u = 0; u < 4; ++u) {
      den += ex[u];
      float w = sl[u] < NN ? ex[u] : 0.f;
      acc.x += w * hv[u].x; acc.y += w * hv[u].y;
      acc.z += w * hv[u].z; acc.w += w * hv[u].w;
    }
  }
  for (; i < m; ++i) {
    float ex = exs[li][i][h];
    den += ex;
    unsigned sl = (unsigned)(srcs[li][i] - b * NN);
    if (sl < NN) {
      float4 hv = *(const float4*)(hbase + (size_t)sl * DM);
      acc.x += ex * hv.x; acc.y += ex * hv.y;
      acc.z += ex * hv.z; acc.w += ex * hv.w;
    }
  }
  float r = 1.f / den;
  acc.x *= r; acc.y *= r; acc.z *= r; acc.w *= r;
  *(float4*)&hgat[((size_t)(d * 4 + v)) * DM + q * 4] = acc;  // node-major
}

// -------- K3: qkv GEMM (M=16000, K=128, N=384, +inb), proven 64x64 tile
__global__ __launch_bounds__(256) void qkv_kernel(const float* __restrict__ hgat,
                                                  const float* __restrict__ inw,
                                                  const float* __restrict__ inb,
                                                  float* __restrict__ qkv) {
  gemm64<128, 0>(blockIdx.x, blockIdx.y, hgat, inw, inb, qkv, 384,
                 nullptr, nullptr, nullptr);
}

// ---------------------------------------------------------------------------
// K4: attention + out_proj fused, staging-free compute phase.
// 8 nodes/block, 256 threads, 500 blocks, 80 KB LDS -> 2 blocks/CU.
// Phase 1: issue each thread's q/k/v fragments (12 float4, coalesced: cg=tid&31
//          fast) + stage outw fully into LDS (64 KB, swizzled k-chunks).
// Phase 2: attention in registers (v3-verified math): S partial over the
//          thread's 4 d, head-reduce = shfl_xor 1/2/4 (head = cg>>3 spans 8
//          consecutive lanes), softmax + aw@v in regs.
// Phase 3: write aoS (16 KB, swizzled), ONE barrier.
// Phase 4: out_proj entirely from LDS (no staging inside -> no hoist/spill
//          hazard), remapped epilogue write.
// ---------------------------------------------------------------------------
__global__ __launch_bounds__(256) void attnout_kernel(const float* __restrict__ qkv,
                                                      const float* __restrict__ outw,
                                                      const float* __restrict__ outb,
                                                      const float* __restrict__ bias,
                                                      float* __restrict__ out) {
  __shared__ float smem[20480];   // 80 KB
  float* outwS = smem;            // [4 kc][128 col][32] swizzled
  float* aoS   = smem + 16384;    // [4 kc][32 row][32] swizzled

  int tid = threadIdx.x;
  int blk = blockIdx.x;
  int cg = tid & 31, rg = tid >> 5;   // d-group (coalescing-fast), node-in-tile
  int node0 = blk * 8;

  // ---- phase 1a: issue q/k/v fragment loads (long latency, hide under 1b) --
  const float4* Q4 = (const float4*)qkv;   // [16000][96] float4
  float4 qf[4], kf[4], vf[4];
#pragma unroll
  for (int vq = 0; vq < 4; ++vq) {
    size_t row = (size_t)((node0 + rg) * 4 + vq) * 96;
    qf[vq] = Q4[row + cg];
    kf[vq] = Q4[row + 32 + cg];
    vf[vq] = Q4[row + 64 + cg];
  }

  // ---- phase 1b: stage outw (4096 float4, 16/thread, coalesced) ----
  const float4* O4 = (const float4*)outw;  // [128 col][32]
#pragma unroll
  for (int tt = 0; tt < 16; ++tt) {
    int g = tt * 256 + tid;                 // f4 index = col*32 + kc*8 + kg
    int kg = g & 7, kc = (g >> 3) & 3, col = g >> 5;
    float4 vv = O4[g];
    *(float4*)&outwS[kc * 4096 + col * 32 + ((kg ^ ((col >> 2) & 7)) << 2)] = vv;
  }

  // ---- phase 2: attention in registers ----
  float S[4][4];
#pragma unroll
  for (int vq = 0; vq < 4; ++vq)
#pragma unroll
    for (int vk = 0; vk < 4; ++vk)
      S[vq][vk] = qf[vq].x * kf[vk].x + qf[vq].y * kf[vk].y
                + qf[vq].z * kf[vk].z + qf[vq].w * kf[vk].w;
#pragma unroll
  for (int vq = 0; vq < 4; ++vq)
#pragma unroll
    for (int vk = 0; vk < 4; ++vk) {
      float s = S[vq][vk];
      s += __shfl_xor(s, 1);
      s += __shfl_xor(s, 2);
      s += __shfl_xor(s, 4);
      S[vq][vk] = s * 0.17677669529663687f;  // 1/sqrt(32)
    }
#pragma unroll
  for (int vq = 0; vq < 4; ++vq) {  // softmax over vk (redundant x8, consistent)
    float mx = fmaxf(fmaxf(S[vq][0], S[vq][1]), fmaxf(S[vq][2], S[vq][3]));
    float e0 = __expf(S[vq][0] - mx), e1 = __expf(S[vq][1] - mx);
    float e2 = __expf(S[vq][2] - mx), e3 = __expf(S[vq][3] - mx);
    float inv = 1.f / (e0 + e1 + e2 + e3);
    S[vq][0] = e0 * inv; S[vq][1] = e1 * inv; S[vq][2] = e2 * inv; S[vq][3] = e3 * inv;
  }

  // ---- phase 3: ao = aw @ v (v is lane-local), write aoS, ONE barrier ----
  {
    int kc = cg >> 3, d4 = cg & 7;
#pragma unroll
    for (int vq = 0; vq < 4; ++vq) {
      float4 o = make_float4(0.f, 0.f, 0.f, 0.f);
#pragma unroll
      for (int vk = 0; vk < 4; ++vk) {
        float w = S[vq][vk];
        o.x += w * vf[vk].x; o.y += w * vf[vk].y;
        o.z += w * vf[vk].z; o.w += w * vf[vk].w;
      }
      int r = rg * 4 + vq;                  // r>>2 == rg
      *(float4*)&aoS[kc * 1024 + r * 32 + ((d4 ^ rg) << 2)] = o;
    }
  }
  __syncthreads();

  // ---- phase 4: out_proj 32x128, pure-LDS compute (no staging inside) ----
  int rg2 = tid & 7, og = tid >> 3;   // rows rg2*4+i, cols og*4+j
  float oc[4][4] = {};
#pragma unroll 2
  for (int kc2 = 0; kc2 < 4; ++kc2) {
#pragma unroll
    for (int q = 0; q < 8; ++q) {
      float4 a[4], bq[4];
      int ga = (q ^ rg2) << 2;
      int gb = (q ^ (og & 7)) << 2;
#pragma unroll
      for (int i = 0; i < 4; ++i)
        a[i] = *(const float4*)&aoS[kc2 * 1024 + (rg2 * 4 + i) * 32 + ga];
#pragma unroll
      for (int j = 0; j < 4; ++j)
        bq[j] = *(const float4*)&outwS[kc2 * 4096 + (og * 4 + j) * 32 + gb];
#pragma unroll
      for (int i = 0; i < 4; ++i)
#pragma unroll
        for (int j = 0; j < 4; ++j)
          oc[i][j] += a[i].x * bq[j].x + a[i].y * bq[j].y
                    + a[i].z * bq[j].z + a[i].w * bq[j].w;
    }
  }

  {  // epilogue: +outb +bias, remap row (node,v) -> (b*4+v)*NN + n
    int nc = og * 4;
    float4 ob = make_float4(outb[nc] + bias[nc], outb[nc + 1] + bias[nc + 1],
                            outb[nc + 2] + bias[nc + 2], outb[nc + 3] + bias[nc + 3]);
#pragma unroll
    for (int i = 0; i < 4; ++i) {
      int node = node0 + rg2, vv = i;
      int bg = node / NN, n = node - bg * NN;
      int om = (bg * 4 + vv) * NN + n;
      *(float4*)&out[(size_t)om * DM + nc] =
          make_float4(oc[i][0] + ob.x, oc[i][1] + ob.y,
                      oc[i][2] + ob.z, oc[i][3] + ob.w);
    }
  }
}

extern "C" void kernel_launch(void* const* d_in, const int* in_sizes, int n_in,
                              void* d_out, int out_size, void* d_ws, size_t ws_size,
                              hipStream_t stream) {
  const float* x    = (const float*)d_in[0];
  const float* W    = (const float*)d_in[1];
  const float* att  = (const float*)d_in[2];
  const float* inw  = (const float*)d_in[3];
  const float* inb  = (const float*)d_in[4];
  const float* outw = (const float*)d_in[5];
  const float* outb = (const float*)d_in[6];
  const float* bias = (const float*)d_in[7];
  const int*   ei   = (const int*)d_in[8];
  float* out = (float*)d_out;

  float* ws = (float*)d_ws;
  float* hbuf  = ws;                       // 2,048,000  (b,v,n)-major h
  float* hgat  = ws + 2100000;             // 2,048,000  node-major
  float* qkv   = ws + 4200000;             // 6,144,000  node-major [16000][384]
  float* ssrc  = ws + 12500000;            // 16,000 } contiguous:
  float* sdst  = ssrc + 16000;             // 16,000 } one 144 KB memset
  int*   cnt   = (int*)(sdst + 16000);     //  4,000 }
  int*   elist = cnt + 4000;               // 192,000 (4000 x CAP)

  // zero ssrc/sdst (rows >=1000 must stay zero) + cnt
  hipMemsetAsync(ssrc, 0, 36000 * sizeof(float), stream);

  k1_kernel<<<500 + EB, 256, 0, stream>>>(x, W, att, hbuf, ssrc, sdst, ei, cnt, elist);
  gather_kernel<<<NTOT / 2, 256, 0, stream>>>(cnt, elist, ssrc, sdst, hbuf, hgat);
  qkv_kernel<<<dim3(250, 6), 256, 0, stream>>>(hgat, inw, inb, qkv);
  attnout_kernel<<<500, 256, 0, stream>>>(qkv, outw, outb, bias, out);
}